// Round 6
// baseline (250.676 us; speedup 1.0000x reference)
//
#include <hip/hip_runtime.h>
#include <stdint.h>

#define Bb 4
#define Tt 2048
#define Dd 1024
#define Hh 16
#define HDd 64
#define Mm 8192   // Bb*Tt

typedef __attribute__((ext_vector_type(8))) short bf16x8;
typedef __attribute__((ext_vector_type(4))) float f32x4;
typedef __attribute__((ext_vector_type(16))) float f32x16;

#define MFMA(a, b, c) __builtin_amdgcn_mfma_f32_16x16x32_bf16(a, b, c, 0, 0, 0)
#define MFMA32(a, b, c) __builtin_amdgcn_mfma_f32_32x32x16_bf16(a, b, c, 0, 0, 0)

#define LOG2E 1.44269504088896340736f
#if __has_builtin(__builtin_amdgcn_exp2f)
#define EXP2(x) __builtin_amdgcn_exp2f(x)
#else
#define EXP2(x) __expf((x) * 0.69314718055994530942f)
#endif

__device__ __forceinline__ unsigned short f2b(float f) {
  union { float f; uint32_t u; } v; v.f = f;
  return (unsigned short)((v.u + 0x7FFFu + ((v.u >> 16) & 1u)) >> 16);
}

// pack two f32 -> bf16x2 via native casts (compiler emits v_cvt_pk_bf16_f32)
__device__ __forceinline__ uint32_t pk2(float a, float b) {
  union { __bf16 h[2]; uint32_t u; } x;
  x.h[0] = (__bf16)a; x.h[1] = (__bf16)b;
  return x.u;
}

__device__ __forceinline__ void gload_lds16(const void* g, void* l) {
  __builtin_amdgcn_global_load_lds(
      (const __attribute__((address_space(1))) void*)g,
      (__attribute__((address_space(3))) void*)l, 16, 0, 0);
}

// ---------------- x f32 -> bf16 ----------------
__global__ __launch_bounds__(256) void k_convert_x(const float* __restrict__ x,
                                                   unsigned short* __restrict__ xb) {
  int i = (blockIdx.x * 256 + threadIdx.x) * 8;
  float4 a = *(const float4*)(x + i);
  float4 b = *(const float4*)(x + i + 4);
  uint4 o;
  o.x = f2b(a.x) | ((uint32_t)f2b(a.y) << 16);
  o.y = f2b(a.z) | ((uint32_t)f2b(a.w) << 16);
  o.z = f2b(b.x) | ((uint32_t)f2b(b.y) << 16);
  o.w = f2b(b.z) | ((uint32_t)f2b(b.w) << 16);
  *(uint4*)(xb + i) = o;
}

// ---------------- W [K][N] f32 -> Wt [N][K] bf16 ----------------
__global__ __launch_bounds__(256) void k_transpose_w(
    const float* __restrict__ Wk, const float* __restrict__ Wq,
    const float* __restrict__ Wv, const float* __restrict__ Wp,
    unsigned short* __restrict__ WkT, unsigned short* __restrict__ WqT,
    unsigned short* __restrict__ WvT, unsigned short* __restrict__ WpT) {
  const float* W; unsigned short* O;
  int wsel = blockIdx.y;
  W = wsel == 0 ? Wk : wsel == 1 ? Wq : wsel == 2 ? Wv : Wp;
  O = wsel == 0 ? WkT : wsel == 1 ? WqT : wsel == 2 ? WvT : WpT;
  __shared__ unsigned short tile[32][36];
  int kb = (blockIdx.x >> 5) << 5;
  int nb = (blockIdx.x & 31) << 5;
  int t = threadIdx.x;
  int r = t >> 3, c4 = (t & 7) << 2;
  float4 v = *(const float4*)(W + (size_t)(kb + r) * Dd + nb + c4);
  tile[r][c4 + 0] = f2b(v.x); tile[r][c4 + 1] = f2b(v.y);
  tile[r][c4 + 2] = f2b(v.z); tile[r][c4 + 3] = f2b(v.w);
  __syncthreads();
  uint2 o;
  o.x = tile[c4 + 0][r] | ((uint32_t)tile[c4 + 1][r] << 16);
  o.y = tile[c4 + 2][r] | ((uint32_t)tile[c4 + 3][r] << 16);
  *(uint2*)(O + (size_t)(nb + r) * Dd + kb + c4) = o;
}

// ---------------- GEMM: A[M][1024] bf16 @ Bt[N][1024]^T + bias ----------------
// qkv=1: Q,K -> [B,H,T,64] (K row-swizzled, Q pre-scaled by 0.125*log2e),
//        V -> [B,H,64,T] (t-swizzled)
// qkv=0: f32 out [M][1024]
__global__ __launch_bounds__(256) void k_gemm(
    const unsigned short* __restrict__ A,
    const unsigned short* __restrict__ Bt0, const unsigned short* __restrict__ Bt1,
    const unsigned short* __restrict__ Bt2,
    const float* __restrict__ bias0, const float* __restrict__ bias1,
    const float* __restrict__ bias2,
    unsigned short* __restrict__ Qb, unsigned short* __restrict__ Kb,
    unsigned short* __restrict__ VTb, float* __restrict__ Pout, int qkv) {
  __shared__ __align__(16) unsigned short Al[128 * 32];
  __shared__ __align__(16) unsigned short Bl[128 * 32];
  int tid = threadIdx.x;
  int lane = tid & 63, wid = tid >> 6;
  int wr = wid >> 1, wc = wid & 1;
  int lq = lane & 15, lh = lane >> 4;
  int mb = blockIdx.x * 128;
  int by = blockIdx.y;
  int widx, nb;
  const unsigned short* Bt; const float* bias;
  if (qkv) {
    widx = by >> 3; nb = (by & 7) << 7;
    Bt = widx == 0 ? Bt0 : (widx == 1 ? Bt1 : Bt2);
    bias = widx == 0 ? bias0 : (widx == 1 ? bias1 : bias2);
  } else {
    widx = 3; nb = by << 7; Bt = Bt0; bias = bias0;
  }

  int srow = (wid << 5) + (lane >> 2);
  int scol = (lane & 3) << 3;
  const unsigned short* Ag = A + (size_t)(mb + srow) * Dd + scol;
  const unsigned short* Bg = Bt + (size_t)(nb + srow) * Dd + scol;
  unsigned short* Alw = Al + (wid << 10);
  unsigned short* Blw = Bl + (wid << 10);

  f32x4 zero = {0.f, 0.f, 0.f, 0.f};
  f32x4 acc[4][4];
#pragma unroll
  for (int m = 0; m < 4; m++)
#pragma unroll
    for (int n = 0; n < 4; n++) acc[m][n] = zero;

  for (int kb = 0; kb < Dd; kb += 32) {
    __syncthreads();
    gload_lds16(Ag + kb, Alw);
    gload_lds16(Ag + kb + 16 * Dd, Alw + 16 * 32);
    gload_lds16(Bg + kb, Blw);
    gload_lds16(Bg + kb + 16 * Dd, Blw + 16 * 32);
    __syncthreads();
    bf16x8 af[4], bf[4];
#pragma unroll
    for (int m = 0; m < 4; m++)
      af[m] = *(const bf16x8*)(Al + (((wr << 6) + (m << 4) + lq) << 5) + (lh << 3));
#pragma unroll
    for (int n = 0; n < 4; n++)
      bf[n] = *(const bf16x8*)(Bl + (((wc << 6) + (n << 4) + lq) << 5) + (lh << 3));
#pragma unroll
    for (int m = 0; m < 4; m++)
#pragma unroll
      for (int n = 0; n < 4; n++) acc[m][n] = MFMA(af[m], bf[n], acc[m][n]);
  }

  int b_idx = mb >> 11;
#pragma unroll
  for (int n = 0; n < 4; n++) {
    int col = nb + (wc << 6) + (n << 4) + lq;
    float bb = bias[col];
    int hh = col >> 6, hd = col & 63;
#pragma unroll
    for (int m = 0; m < 4; m++) {
      int row0 = mb + (wr << 6) + (m << 4) + (lh << 2);
      int t0 = row0 & 2047;
      if (widx == 3) {
#pragma unroll
        for (int r = 0; r < 4; r++)
          Pout[(size_t)(row0 + r) * Dd + col] = acc[m][n][r] + bb;
      } else if (widx == 2) {
        float v0 = acc[m][n][0] + bb, v1 = acc[m][n][1] + bb;
        float v2 = acc[m][n][2] + bb, v3 = acc[m][n][3] + bb;
        uint2 pv;
        pv.x = f2b(v0) | ((uint32_t)f2b(v1) << 16);
        pv.y = f2b(v2) | ((uint32_t)f2b(v3) << 16);
        int t0s = t0 ^ ((hd & 7) << 3);  // V swizzle: t 16B-block ^= hd&7
        *(uint2*)(VTb + ((size_t)(b_idx * 16 + hh) * 64 + hd) * Tt + t0s) = pv;
      } else {
        unsigned short* O = (widx == 0) ? Qb : Kb;
        float sc = (widx == 0) ? (0.125f * LOG2E) : 1.0f;  // fold 1/sqrt(HD)*log2e into Q
#pragma unroll
        for (int r = 0; r < 4; r++) {
          float v = (acc[m][n][r] + bb) * sc;
          int trow = t0 + r;
          int hds = (widx == 0) ? hd : (hd ^ ((trow & 7) << 3));  // K swizzle
          O[((size_t)(b_idx * 16 + hh) * Tt + trow) * 64 + hds] = f2b(v);
        }
      }
    }
  }
}

// ---------------- flash attention (causal), Q pre-scaled by 0.125*log2e ----------
// block = 64 q rows, 4 waves = (q-half qh, kv-half h). Each 64-row KV tile is
// staged once (global_load_lds, double buffer); waves compute their (qh,h)
// quadrant => ~full wave activity. No-max softmax: (O,lsum) additive across h,
// combined via LDS at block end. Swapped QK^T, register-local P pack.
__global__ __launch_bounds__(256, 4) void k_attn(
    const unsigned short* __restrict__ Qb, const unsigned short* __restrict__ Kb,
    const unsigned short* __restrict__ VTb, unsigned short* __restrict__ yb) {
  __shared__ __align__(16) unsigned short KL[2][4096];
  __shared__ __align__(16) unsigned short VL[2][4096];
  int raw = blockIdx.x;
  int blk = ((raw & 7) << 9) | (raw >> 3);   // XCD chunk: same head -> same XCD L2
  int bh = blk >> 5;
  int qt = 31 - (blk & 31);                  // heavy q-tiles first
  int tid = threadIdx.x, lane = tid & 63, w = tid >> 6;
  int qh = w >> 1, h = w & 1;
  int l31 = lane & 31, hi = lane >> 5;
  const unsigned short* __restrict__ Qh = Qb + (size_t)bh * Tt * 64;
  const unsigned short* __restrict__ Kh = Kb + (size_t)bh * Tt * 64;
  const unsigned short* __restrict__ Vh = VTb + (size_t)bh * 64 * Tt;
  int qg = (qt << 6) + (qh << 5);

  // Q B-fragments: lane holds Q[qg+l31][16c + 8hi + j]
  bf16x8 qf[4];
#pragma unroll
  for (int c = 0; c < 4; c++)
    qf[c] = *(const bf16x8*)(Qh + (size_t)(qg + l31) * 64 + (c << 4) + (hi << 3));

  f32x16 acc0, acc1;
#pragma unroll
  for (int i = 0; i < 16; i++) { acc0[i] = 0.f; acc1[i] = 0.f; }
  float lsum = 0.f;

  int srow = lane >> 3, scol = (lane & 7) << 3;
  int rowb = w << 4;         // wave stages 16 rows of K and of V per tile
  int swz = l31 & 7;

  // prologue: stage tile 0 into buf 0
  gload_lds16(Kh + (size_t)(rowb + srow) * 64 + scol, &KL[0][rowb << 6]);
  gload_lds16(Kh + (size_t)(rowb + 8 + srow) * 64 + scol, &KL[0][(rowb + 8) << 6]);
  gload_lds16(Vh + (size_t)(rowb + srow) * Tt + scol, &VL[0][rowb << 6]);
  gload_lds16(Vh + (size_t)(rowb + 8 + srow) * Tt + scol, &VL[0][(rowb + 8) << 6]);
  __syncthreads();

  int cur = 0;
  for (int jt = 0; jt <= qt; ++jt) {
    if (jt < qt) {  // stage next tile into the other buffer (hides under compute)
      int kv1 = (jt + 1) << 6;
      gload_lds16(Kh + (size_t)(kv1 + rowb + srow) * 64 + scol, &KL[cur ^ 1][rowb << 6]);
      gload_lds16(Kh + (size_t)(kv1 + rowb + 8 + srow) * 64 + scol,
                  &KL[cur ^ 1][(rowb + 8) << 6]);
      gload_lds16(Vh + (size_t)(rowb + srow) * Tt + kv1 + scol, &VL[cur ^ 1][rowb << 6]);
      gload_lds16(Vh + (size_t)(rowb + 8 + srow) * Tt + kv1 + scol,
                  &VL[cur ^ 1][(rowb + 8) << 6]);
    }
    int d = qg - (jt << 6) - (h << 5);  // wave-uniform; 0 => diagonal quadrant
    if (d >= 0) {
      const unsigned short* KB = &KL[cur][0];
      const unsigned short* VB = &VL[cur][0];
      bf16x8 kf[4];
      int krowb = ((h << 5) + l31) << 6;
#pragma unroll
      for (int c = 0; c < 4; c++)
        kf[c] = *(const bf16x8*)(KB + krowb + ((((c << 1) + hi) ^ swz) << 3));
      f32x16 s;
#pragma unroll
      for (int i = 0; i < 16; i++) s[i] = 0.f;
#pragma unroll
      for (int c = 0; c < 4; c++) s = MFMA32(kf[c], qf[c], s);
      float p[16];
      if (d == 0) {
#pragma unroll
        for (int r = 0; r < 16; r++) {
          int krow = (r & 3) + ((r >> 2) << 3) + (hi << 2);
          p[r] = EXP2(krow > l31 ? -1e30f : s[r]);
        }
      } else {
#pragma unroll
        for (int r = 0; r < 16; r++) p[r] = EXP2(s[r]);
      }
      lsum += (((p[0] + p[1]) + (p[2] + p[3])) + ((p[4] + p[5]) + (p[6] + p[7])))
            + (((p[8] + p[9]) + (p[10] + p[11])) + ((p[12] + p[13]) + (p[14] + p[15])));
      // V fragments: B slots for kv rows 32h+16cc+sigma, column half n2v
      union { uint2 u2[2]; bf16x8 v; } vf[2][2];
#pragma unroll
      for (int n2v = 0; n2v < 2; n2v++) {
        int vrowb = ((n2v << 5) + l31) << 6;
#pragma unroll
        for (int cc = 0; cc < 2; cc++) {
          int blk0 = (h << 2) + (cc << 1);
          vf[n2v][cc].u2[0] = *(const uint2*)(VB + vrowb + ((blk0 ^ swz) << 3) + (hi << 2));
          vf[n2v][cc].u2[1] =
              *(const uint2*)(VB + vrowb + (((blk0 + 1) ^ swz) << 3) + (hi << 2));
        }
      }
      // pack P into A-fragments (register-local; slot order matches V's b64 reads)
      union { uint32_t u[4]; bf16x8 v; } ap0, ap1;
#pragma unroll
      for (int g = 0; g < 4; g++) {
        ap0.u[g] = pk2(p[2 * g], p[2 * g + 1]);
        ap1.u[g] = pk2(p[8 + 2 * g], p[8 + 2 * g + 1]);
      }
      acc0 = MFMA32(ap0.v, vf[0][0].v, acc0);
      acc1 = MFMA32(ap0.v, vf[1][0].v, acc1);
      acc0 = MFMA32(ap1.v, vf[0][1].v, acc0);
      acc1 = MFMA32(ap1.v, vf[1][1].v, acc1);
    }
    __syncthreads();
    cur ^= 1;
  }

  lsum += __shfl_xor(lsum, 32);

  // ---- combine h=0 / h=1 partials (additive: no-max softmax) ----
  float* Of = (float*)&KL[0][0];   // [2 qh][32 q][64 hd] f32 = 16 KB (reuses KL)
  float* Ls = (float*)&VL[0][0];   // [2 qh][32 q]
  if (h == 0) {
#pragma unroll
    for (int r = 0; r < 16; r++) {
      int qr = (r & 3) + ((r >> 2) << 3) + (hi << 2);
      int ro = ((qh << 5) + qr) << 6;
      Of[ro + l31] = acc0[r];
      Of[ro + l31 + 32] = acc1[r];
    }
    if (hi == 0) Ls[(qh << 5) + l31] = lsum;
  }
  __syncthreads();
  if (h == 1) {
    float inv = 1.0f / (lsum + Ls[(qh << 5) + l31]);
    int bb = bh >> 4, hh = bh & 15;
#pragma unroll
    for (int r = 0; r < 16; r++) {
      int qr = (r & 3) + ((r >> 2) << 3) + (hi << 2);
      float invq = __shfl(inv, qr);
      int ro = ((qh << 5) + qr) << 6;
      size_t base = ((size_t)(bb * Tt + qg + qr)) * Dd + (hh << 6) + l31;
      yb[base] = f2b((acc0[r] + Of[ro + l31]) * invq);
      yb[base + 32] = f2b((acc1[r] + Of[ro + l31 + 32]) * invq);
    }
  }
}

extern "C" void kernel_launch(void* const* d_in, const int* in_sizes, int n_in,
                              void* d_out, int out_size, void* d_ws, size_t ws_size,
                              hipStream_t stream) {
  const float* x = (const float*)d_in[0];
  const float* Wk = (const float*)d_in[1];
  const float* bk = (const float*)d_in[2];
  const float* Wq = (const float*)d_in[3];
  const float* bq = (const float*)d_in[4];
  const float* Wv = (const float*)d_in[5];
  const float* bv = (const float*)d_in[6];
  const float* Wp = (const float*)d_in[7];
  const float* bp = (const float*)d_in[8];
  float* out = (float*)d_out;

  char* ws = (char*)d_ws;
  unsigned short* xb  = (unsigned short*)(ws);                       // 16MB
  unsigned short* WkT = (unsigned short*)(ws + (16ull << 20));       // 2MB each
  unsigned short* WqT = (unsigned short*)(ws + (18ull << 20));
  unsigned short* WvT = (unsigned short*)(ws + (20ull << 20));
  unsigned short* WpT = (unsigned short*)(ws + (22ull << 20));
  unsigned short* Qb  = (unsigned short*)(ws + (24ull << 20));       // 16MB
  unsigned short* Kb  = (unsigned short*)(ws + (40ull << 20));       // 16MB
  unsigned short* VTb = (unsigned short*)(ws + (56ull << 20));       // 16MB
  unsigned short* yb  = (unsigned short*)(ws + (72ull << 20));       // 16MB (ends 88MB)

  k_convert_x<<<4096, 256, 0, stream>>>(x, xb);
  k_transpose_w<<<dim3(1024, 4), 256, 0, stream>>>(Wk, Wq, Wv, Wp, WkT, WqT, WvT, WpT);
  k_gemm<<<dim3(64, 24), 256, 0, stream>>>(xb, WqT, WkT, WvT, bq, bk, bv,
                                           Qb, Kb, VTb, nullptr, 1);
  k_attn<<<4096, 256, 0, stream>>>(Qb, Kb, VTb, yb);
  k_gemm<<<dim3(64, 8), 256, 0, stream>>>(yb, WpT, nullptr, nullptr, bp, nullptr, nullptr,
                                          nullptr, nullptr, nullptr, out, 0);
}